// Round 5
// baseline (81.743 us; speedup 1.0000x reference)
//
#include <hip/hip_runtime.h>

#define NN 2048
#define KK 8
#define BB 32
#define TT 20

__global__ __launch_bounds__(1024) void osci_kernel(
    const float* __restrict__ coupling,   // [B,N,K]
    const float* __restrict__ phase0,     // [B,N]
    const float* __restrict__ omega,      // [B,N]
    const int*   __restrict__ conn,       // [N,K]
    float*       __restrict__ out)        // [T+1,B,N]
{
    const int b   = blockIdx.x;
    const int tid = threadIdx.x;

    // Two double-buffered tables; buf1 accesses fold to ds immediates:
    //   ph_tab: +8192 bytes, sc_tab: +16384 bytes
    __shared__ float  ph_tab[2 * NN];     // phase table  (sin-path gathers, b32)
    __shared__ float2 sc_tab[2 * NN];     // (sin,cos)    (table-path gathers, b64)

    // per-thread: osc0 = tid (sin-path), osc1 = tid+1024 (table-path)
    int   cidx[2][KK];
    float w[2][KK];
    float inv_n[2];
    float om[2];
    float ph[2];
    float si1, ci1;                        // own sin/cos for osc1 (table path)

    for (int t = 0; t < 2; ++t) {
        const int i = tid + t * 1024;
        float p = phase0[b * NN + i];
        ph[t] = p;
        float s, c;
        __sincosf(p, &s, &c);
        if (t == 1) { si1 = s; ci1 = c; }
        ph_tab[i] = p;
        sc_tab[i] = make_float2(s, c);
        out[(size_t)b * NN + i] = p;      // out[0, b, i] = phase0
        om[t] = omega[b * NN + i];

        // vectorized setup loads (rows are 32B-aligned)
        const int4*   c4 = (const int4*)  &conn[i * KK];
        const float4* w4 = (const float4*)&coupling[((size_t)b * NN + i) * KK];
        int4   ja = c4[0], jb = c4[1];
        float4 va = w4[0], vb = w4[1];
        int   jj[KK] = { ja.x, ja.y, ja.z, ja.w, jb.x, jb.y, jb.z, jb.w };
        float vv[KK] = { va.x, va.y, va.z, va.w, vb.x, vb.y, vb.z, vb.w };

        // last-wins scatter dedup: entry k vanishes if any k2>k hits same column;
        // n = count of surviving nonzero dense-row entries
        int cnt = 0;
        #pragma unroll
        for (int k = 0; k < KK; ++k) {
            bool over = false;
            #pragma unroll
            for (int k2 = k + 1; k2 < KK; ++k2) over = over || (jj[k2] == jj[k]);
            if (over) vv[k] = 0.0f;
            if (vv[k] != 0.0f) ++cnt;
        }
        #pragma unroll
        for (int k = 0; k < KK; ++k) { cidx[t][k] = jj[k]; w[t][k] = vv[k]; }
        inv_n[t] = 1.0f / (float)cnt;     // cnt >= 1 always (last write survives)
    }
    __syncthreads();   // setup: full drain once is fine

    float* outp = out + ((size_t)BB + b) * NN;   // &out[1][b][0]

    #pragma unroll 1
    for (int sp = 0; sp < TT; sp += 2) {
        // ================ even step: read buf0, write buf1 ================
        {
            // osc0: sin-path (trans pipe) — gather phi_j as b32
            const float p0 = ph[0];
            float acc = 0.0f;
            #pragma unroll
            for (int k = 0; k < KK; ++k) {
                acc += w[0][k] * __sinf(ph_tab[cidx[0][k]] - p0);
            }
            const float pn0 = p0 + acc * inv_n[0] + om[0];

            // osc1: table-path (LDS+VALU pipes) — gather (sin,cos) as b64
            float cs = 0.0f, cc = 0.0f;
            #pragma unroll
            for (int k = 0; k < KK; ++k) {
                const float2 v = sc_tab[cidx[1][k]];
                cs += w[1][k] * v.x;
                cc += w[1][k] * v.y;
            }
            const float pn1 = ph[1] + (cs * ci1 - cc * si1) * inv_n[1] + om[1];

            ph[0] = pn0; ph[1] = pn1;
            float s0, c0;
            __sincosf(pn0, &s0, &c0);
            __sincosf(pn1, &si1, &ci1);
            ph_tab[NN + tid]        = pn0;
            ph_tab[NN + tid + 1024] = pn1;
            sc_tab[NN + tid]        = make_float2(s0, c0);
            sc_tab[NN + tid + 1024] = make_float2(si1, ci1);
            outp[tid]        = pn0;       // fire-and-forget HBM stores
            outp[tid + 1024] = pn1;
        }
        // LDS-only barrier: no vmcnt drain
        asm volatile("s_waitcnt lgkmcnt(0)" ::: "memory");
        __builtin_amdgcn_s_barrier();
        asm volatile("" ::: "memory");
        outp += (size_t)BB * NN;

        // ================ odd step: read buf1, write buf0 ================
        {
            const float p0 = ph[0];
            float acc = 0.0f;
            #pragma unroll
            for (int k = 0; k < KK; ++k) {
                acc += w[0][k] * __sinf(ph_tab[NN + cidx[0][k]] - p0);
            }
            const float pn0 = p0 + acc * inv_n[0] + om[0];

            float cs = 0.0f, cc = 0.0f;
            #pragma unroll
            for (int k = 0; k < KK; ++k) {
                const float2 v = sc_tab[NN + cidx[1][k]];
                cs += w[1][k] * v.x;
                cc += w[1][k] * v.y;
            }
            const float pn1 = ph[1] + (cs * ci1 - cc * si1) * inv_n[1] + om[1];

            ph[0] = pn0; ph[1] = pn1;
            float s0, c0;
            __sincosf(pn0, &s0, &c0);
            __sincosf(pn1, &si1, &ci1);
            ph_tab[tid]        = pn0;
            ph_tab[tid + 1024] = pn1;
            sc_tab[tid]        = make_float2(s0, c0);
            sc_tab[tid + 1024] = make_float2(si1, ci1);
            outp[tid]        = pn0;
            outp[tid + 1024] = pn1;
        }
        asm volatile("s_waitcnt lgkmcnt(0)" ::: "memory");
        __builtin_amdgcn_s_barrier();
        asm volatile("" ::: "memory");
        outp += (size_t)BB * NN;
    }
}

extern "C" void kernel_launch(void* const* d_in, const int* in_sizes, int n_in,
                              void* d_out, int out_size, void* d_ws, size_t ws_size,
                              hipStream_t stream) {
    const float* coupling = (const float*)d_in[0];   // [B,N,K]
    const float* phase0   = (const float*)d_in[1];   // [B,N]
    const float* omega    = (const float*)d_in[2];   // [B,N]
    const int*   conn     = (const int*)d_in[3];     // [N,K]
    float* out = (float*)d_out;                      // [T+1,B,N]

    osci_kernel<<<BB, 1024, 0, stream>>>(coupling, phase0, omega, conn, out);
}